// Round 9
// baseline (2276.847 us; speedup 1.0000x reference)
//
#include <hip/hip_runtime.h>
#include <hip/hip_bf16.h>
#include <hip/hip_fp16.h>
#include <stdint.h>

// ============================================================================
// LSTMEncoder (3-layer Keras LSTM, per-gate input dropout 0.6, threefry RNG)
//   L0: x[256,1024,128] -> h0 ; L1: h0 -> h1 ; L2: h1 -> h_last[256,64] (f32)
// Round 9: rec step-overhead attack. rec2(VALU)=1640 cyc/step, rec3(MFMA)=1785
// => matvec engine irrelevant; overhead = per-step global z loads + store acks
// + barrier discipline. rec4:
//   - z tiles (32 steps) staged to LDS via global_load_lds w16, double-buffered;
//     ONE vmcnt(0) per 32 steps. Per-step z = 4 ds_read_u16 (lgkm scope).
//   - Hseq stores batched 8x in regs (static idx), burst per 8 steps.
//   - m201 barrier pattern: lgkmcnt(0)+sched_barrier fences, 1 s_barrier/step,
//     double-buffered h. No "memory" clobbers, no per-step vmcnt.
//   gemm_mfma / mask_kernel unchanged (verified round 6).
// Workspace: masks(1.5MB) + z_in f16(256MB) + h0,h1 f16(64MB ea)
// ============================================================================

#define MODE_F32  0
#define MODE_F16  2

typedef _Float16 f16x8 __attribute__((ext_vector_type(8)));
typedef float    f32x4 __attribute__((ext_vector_type(4)));

__device__ __forceinline__ float h16f(uint16_t b){
  __half_raw hr; hr.x = b; return __half2float(__half(hr));
}

// ---------------- dtype helpers ----------------
template<int M>
__device__ __forceinline__ void cvt8(const void* p, size_t i, float* o){
  if constexpr (M == MODE_F32){
    const float* f = (const float*)p + i;
    float4 a = *(const float4*)f;
    float4 b = *(const float4*)(f + 4);
    o[0]=a.x; o[1]=a.y; o[2]=a.z; o[3]=a.w;
    o[4]=b.x; o[5]=b.y; o[6]=b.z; o[7]=b.w;
  } else {
    uint4 r = *(const uint4*)((const uint16_t*)p + i);
    uint32_t hw[4] = {r.x, r.y, r.z, r.w};
    #pragma unroll
    for (int q=0;q<4;q++){
      o[2*q]   = h16f((uint16_t)(hw[q] & 0xffffu));
      o[2*q+1] = h16f((uint16_t)(hw[q] >> 16));
    }
  }
}

// ---------------- K2: JAX threefry2x32 (partitionable) masks ----------------
__device__ __forceinline__ void tf2x32(uint32_t k0, uint32_t k1,
                                       uint32_t& x0, uint32_t& x1){
  uint32_t ks2 = k0 ^ k1 ^ 0x1BD11BDAu;
  x0 += k0; x1 += k1;
#define TF_R(r) { x0 += x1; x1 = (x1<<r)|(x1>>(32-r)); x1 ^= x0; }
  TF_R(13) TF_R(15) TF_R(26) TF_R(6)  x0 += k1;  x1 += ks2 + 1u;
  TF_R(17) TF_R(29) TF_R(16) TF_R(24) x0 += ks2; x1 += k0  + 2u;
  TF_R(13) TF_R(15) TF_R(26) TF_R(6)  x0 += k0;  x1 += k1  + 3u;
  TF_R(17) TF_R(29) TF_R(16) TF_R(24) x0 += k1;  x1 += ks2 + 4u;
  TF_R(13) TF_R(15) TF_R(26) TF_R(6)  x0 += ks2; x1 += k0  + 5u;
#undef TF_R
}

__device__ __forceinline__ float bern_mask(uint32_t bits){
  float u = __uint_as_float((bits >> 9) | 0x3f800000u) - 1.0f;
  return (u < 0.4f) ? 2.5f : 0.0f;
}

__global__ void mask_kernel(float* __restrict__ masks){
  int gid = blockIdx.x * 256 + threadIdx.x;     // [0, 3*131072)
  int layer = gid >> 17;
  uint32_t i = (uint32_t)(gid & 131071);
  uint32_t k0 = 0u, k1 = (uint32_t)layer;
  tf2x32(0u, 4347u, k0, k1);                    // foldlike split
  uint32_t x0 = 0u, x1 = i;
  tf2x32(k0, k1, x0, x1);                       // partitionable bits
  masks[gid] = bern_mask(x0 ^ x1);
}

// ---------------- K3: input-projection GEMM via MFMA f16 ----------------
// (unchanged — verified round 6)
template<int U, int AM>
__global__ __launch_bounds__(256) void gemm_mfma(
    const void*  __restrict__ A,
    const float* __restrict__ W,
    const float* __restrict__ bias,
    const float* __restrict__ maskL,   // [4][256][128]
    __half* __restrict__ Z)
{
  constexpr int WC   = 4*U;
  constexpr int HALF = U/2;
  __shared__ _Float16 As [128][128];
  __shared__ _Float16 Bst[U  ][128];   // transposed: [col][k]
  const int tid  = threadIdx.x;
  const int r0   = blockIdx.x * 128;
  const int gate = blockIdx.y;
  const int bb   = blockIdx.x >> 3;    // batch (8 row-tiles per batch)
  const float* mrow = maskL + gate*32768 + bb*128;

  // ---- stage A: (x or h) * mask -> f16, swizzled ----
  {
    const int r  = tid >> 1;
    const int kh = (tid & 1) * 64;
    #pragma unroll
    for (int c=0;c<8;c++){
      int k0 = kh + c*8;
      float av[8]; cvt8<AM>(A, (size_t)(r0+r)*128 + k0, av);
      float4 m0 = *(const float4*)(mrow+k0);
      float4 m1 = *(const float4*)(mrow+k0+4);
      _Float16* dst = &As[r][k0 ^ ((r&7)<<3)];
      dst[0]=(_Float16)(av[0]*m0.x); dst[1]=(_Float16)(av[1]*m0.y);
      dst[2]=(_Float16)(av[2]*m0.z); dst[3]=(_Float16)(av[3]*m0.w);
      dst[4]=(_Float16)(av[4]*m1.x); dst[5]=(_Float16)(av[5]*m1.y);
      dst[6]=(_Float16)(av[6]*m1.z); dst[7]=(_Float16)(av[7]*m1.w);
    }
  }
  // ---- stage B: Wk gate slice, transposed + swizzled ----
  {
    const int d  = tid >> 1;
    const int ch = (tid & 1) * HALF;
    #pragma unroll
    for (int cc=0; cc<HALF/8; ++cc){
      int c0 = ch + cc*8;
      const float* wp = W + (size_t)d*WC + gate*U + c0;
      float4 w0 = *(const float4*)wp;
      float4 w1 = *(const float4*)(wp+4);
      float wv[8] = {w0.x,w0.y,w0.z,w0.w,w1.x,w1.y,w1.z,w1.w};
      #pragma unroll
      for (int q=0;q<8;q++){
        int c = c0 + q;
        Bst[c][d ^ ((c&7)<<3)] = (_Float16)wv[q];
      }
    }
  }
  __syncthreads();

  // ---- MFMA compute ----
  const int l  = tid & 63;
  const int w  = tid >> 6;
  const int lr = l & 15;
  const int kg = (l >> 4) * 8;
  constexpr int MF = (U==128) ? 4 : 2;         // m-frags per wave
  const int wr = (U==128) ? ((w>>1)*64) : (w*32);
  const int wc = (U==128) ? ((w&1)*64) : 0;

  f32x4 zz = {0.f,0.f,0.f,0.f};
  f32x4 acc[MF][4];
  #pragma unroll
  for (int m=0;m<MF;m++)
    #pragma unroll
    for (int n=0;n<4;n++) acc[m][n] = zz;

  #pragma unroll
  for (int ks=0; ks<4; ++ks){
    const int kb = ks*32 + kg;
    f16x8 af[MF], bf[4];
    #pragma unroll
    for (int m=0;m<MF;m++){
      int r = wr + m*16 + lr;
      af[m] = *(const f16x8*)&As[r][kb ^ ((r&7)<<3)];
    }
    #pragma unroll
    for (int n=0;n<4;n++){
      int c = wc + n*16 + lr;
      bf[n] = *(const f16x8*)&Bst[c][kb ^ ((c&7)<<3)];
    }
    #pragma unroll
    for (int m=0;m<MF;m++)
      #pragma unroll
      for (int n=0;n<4;n++)
        acc[m][n] = __builtin_amdgcn_mfma_f32_16x16x32_f16(af[m], bf[n], acc[m][n], 0, 0, 0);
  }

  // ---- epilogue: + bias, f16 planar stores ----
  const int crow = (l>>4)*4;
  float bv[4];
  #pragma unroll
  for (int n=0;n<4;n++) bv[n] = bias[gate*U + wc + n*16 + lr];
  #pragma unroll
  for (int m=0;m<MF;m++){
    #pragma unroll
    for (int n=0;n<4;n++){
      int cc = wc + n*16 + lr;
      #pragma unroll
      for (int j=0;j<4;j++){
        int rr = wr + m*16 + crow + j;
        Z[(size_t)(r0+rr)*WC + gate*U + cc] = __float2half(acc[m][n][j] + bv[n]);
      }
    }
  }
}

// ---------------- K4: recurrence v4 (MFMA + LDS z tiles) ----------------
__device__ __forceinline__ float sigf(float x){ return 1.0f/(1.0f + __expf(-x)); }
__device__ __forceinline__ float tanh_f(float x){ return 1.0f - 2.0f/(__expf(2.0f*x) + 1.0f); }

// 1 block per batch row, 4U threads (U/16 waves... 8 waves U=128, 4 waves U=64).
// Wave w owns u-block w*16..+15; Wr slice as B-frags in VGPR/AGPR (loaded once).
// z: 32-step tiles in LDS (global_load_lds w16, double-buffered, linear copy).
// h: f16 double-buffered in LDS, one raw s_barrier per step (m201 pattern).
template<int U, bool SEQ>
__global__ __launch_bounds__(4*U, 1) void rec4_kernel(
    const __half* __restrict__ Zin,     // [256][1024][4U] planar [g*U+u]
    const float*  __restrict__ Wr,      // [U][4U]
    __half* __restrict__ Hseq,          // [256][1024][U]  (SEQ)
    float*  __restrict__ Hlast)         // [256][U]        (!SEQ)
{
  constexpr int C   = 4*U;
  constexpr int KS  = U/32;             // mfma k-steps over h-dim
  constexpr int TS  = 32;               // steps per z tile
  constexpr int TBH = TS*C;             // halfwords per tile
  constexpr int NCH = 4;                // (TS*C*2) / (4U*16) = 4 for U=64/128
  const int row = blockIdx.x;
  const int tid = threadIdx.x;
  const int l   = tid & 63;
  const int w   = tid >> 6;
  const int lr  = l & 15;
  const int kg  = (l >> 4) * 8;
  const int u   = w*16 + lr;

  __shared__ _Float16 zt[2][TBH];       // z tiles (64KB @U=128)
  __shared__ _Float16 hbuf[2][U];

  // B fragments: bf[g][ks][j] = Wr[ks*32+kg+j][g*U + u]  (one-time load)
  f16x8 bf[4][KS];
  #pragma unroll
  for (int g=0; g<4; ++g)
    #pragma unroll
    for (int ks=0; ks<KS; ++ks)
      #pragma unroll
      for (int j=0; j<8; ++j)
        bf[g][ks][j] = (_Float16)Wr[(size_t)(ks*32 + kg + j)*C + g*U + u];

  if (tid < U) hbuf[0][tid] = (_Float16)0.0f;
  float cst = 0.0f;

  const char* zrow = (const char*)Zin + (size_t)row*1024*C*2;
  // stage tile -> LDS buffer (linear copy; dest = uniform base + lane*16)
  auto stage = [&](int tile, int buf){
    const char* gsrc = zrow + (size_t)tile*TBH*2;
    char* lbase = (char*)&zt[buf][0];
    #pragma unroll
    for (int c=0; c<NCH; ++c){
      int off = c*(4*U*16) + tid*16;
      __builtin_amdgcn_global_load_lds(
          (const uint32_t*)(gsrc + off),
          (uint32_t*)(lbase + c*(4*U*16) + w*1024),
          16, 0, 0);
    }
  };
  stage(0, 0);

  uint16_t* hsq = nullptr;
  if constexpr (SEQ) hsq = (uint16_t*)Hseq + (size_t)row*1024*U + u;

  // wait: tile0 staged (vm) + hbuf init (lgkm), all waves
  __builtin_amdgcn_sched_barrier(0);
  asm volatile("s_waitcnt vmcnt(0) lgkmcnt(0)");
  __builtin_amdgcn_s_barrier();
  __builtin_amdgcn_sched_barrier(0);

  for (int tile=0; tile<1024/TS; ++tile){
    const int buf = tile & 1;
    if (tile+1 < 1024/TS) stage(tile+1, buf^1);

    #pragma unroll 1
    for (int s8=0; s8<TS/8; ++s8){
      uint16_t hr[8];
      #pragma unroll
      for (int r8=0; r8<8; ++r8){               // static r8 -> static hr index
        const int s  = s8*8 + r8;
        const int tt = tile*TS + s;
        const int hb = r8 & 1;                  // == tt&1 (tile*TS, s8*8 even)
        // ---- LDS reads: h frags + z gates ----
        f16x8 af[KS];
        #pragma unroll
        for (int ks=0; ks<KS; ++ks)
          af[ks] = *(const f16x8*)&hbuf[hb][ks*32 + kg];
        float zg0 = (float)zt[buf][s*C         + u];
        float zg1 = (float)zt[buf][s*C +   U   + u];
        float zg2 = (float)zt[buf][s*C + 2*U   + u];
        float zg3 = (float)zt[buf][s*C + 3*U   + u];
        __builtin_amdgcn_sched_barrier(0);
        asm volatile("s_waitcnt lgkmcnt(0)");
        __builtin_amdgcn_sched_barrier(0);
        // ---- z + h.Wr on matrix pipe (D rows identical) ----
        f32x4 acc[4];
        acc[0] = (f32x4){zg0,zg0,zg0,zg0};
        acc[1] = (f32x4){zg1,zg1,zg1,zg1};
        acc[2] = (f32x4){zg2,zg2,zg2,zg2};
        acc[3] = (f32x4){zg3,zg3,zg3,zg3};
        #pragma unroll
        for (int g=0; g<4; ++g)
          #pragma unroll
          for (int ks=0; ks<KS; ++ks)
            acc[g] = __builtin_amdgcn_mfma_f32_16x16x32_f16(af[ks], bf[g][ks], acc[g], 0, 0, 0);
        // ---- gates on all lanes (no divergence) ----
        float gi = sigf(acc[0][0]);
        float gf = sigf(acc[1][0]);
        float gg = tanh_f(acc[2][0]);
        float go = sigf(acc[3][0]);
        cst = fmaf(gf, cst, gi*gg);
        float h = go * tanh_f(cst);
        __half hh = __float2half(h);
        hr[r8] = *(uint16_t*)&hh;
        if (l < 16){
          hbuf[hb ^ 1][u] = *(_Float16*)&hh;
          if constexpr (!SEQ){
            if (tt == 1023) Hlast[(size_t)row*U + u] = h;
          }
        }
        // ---- publish h: drain my ds_write, barrier (vm stays in flight) ----
        __builtin_amdgcn_sched_barrier(0);
        asm volatile("s_waitcnt lgkmcnt(0)");
        __builtin_amdgcn_s_barrier();
        __builtin_amdgcn_sched_barrier(0);
      }
      // ---- burst Hseq stores (8 steps, one vm batch; drained at tile edge) --
      if constexpr (SEQ){
        if (l < 16){
          uint16_t* hp = hsq + (size_t)(tile*TS + s8*8)*U;
          #pragma unroll
          for (int j=0; j<8; ++j) hp[(size_t)j*U] = hr[j];
        }
      }
    }
    // ---- tile edge: per-wave staging done, then all waves ----
    if (tile+1 < 1024/TS){
      __builtin_amdgcn_sched_barrier(0);
      asm volatile("s_waitcnt vmcnt(0)");
      __builtin_amdgcn_s_barrier();
      __builtin_amdgcn_sched_barrier(0);
    }
  }
}

// ---------------- host launch ----------------
extern "C" void kernel_launch(void* const* d_in, const int* in_sizes, int n_in,
                              void* d_out, int out_size, void* d_ws, size_t ws_size,
                              hipStream_t stream)
{
  (void)in_sizes; (void)n_in; (void)out_size; (void)ws_size;
  const void*  x   = d_in[0];
  const float* Wk0 = (const float*)d_in[1];
  const float* Wr0 = (const float*)d_in[2];
  const float* b0  = (const float*)d_in[3];
  const float* Wk1 = (const float*)d_in[4];
  const float* Wr1 = (const float*)d_in[5];
  const float* b1  = (const float*)d_in[6];
  const float* Wko = (const float*)d_in[7];
  const float* Wro = (const float*)d_in[8];
  const float* bo  = (const float*)d_in[9];

  char* ws = (char*)d_ws;
  float*  masks = (float*)(ws + 256);                           // 1.5 MB
  __half* zin   = (__half*)(ws + 256 + 3*131072*4);             // 256 MB
  __half* h0    = (__half*)((char*)zin + (size_t)262144*512*2); // 64 MB
  __half* h1    = h0 + (size_t)262144*128;                      // 64 MB
  float*  out   = (float*)d_out;

  mask_kernel<<<1536, 256, 0, stream>>>(masks);

  // layer 0 (A = x, f32)
  gemm_mfma<128, MODE_F32><<<dim3(2048,4), 256, 0, stream>>>(x, Wk0, b0, masks, zin);
  rec4_kernel<128, true><<<256, 512, 0, stream>>>(zin, Wr0, (__half*)h0, nullptr);
  // layer 1 (A = h0, f16 ours)
  gemm_mfma<128, MODE_F16><<<dim3(2048,4), 256, 0, stream>>>(h0, Wk1, b1, masks + 131072, zin);
  rec4_kernel<128, true><<<256, 512, 0, stream>>>(zin, Wr1, (__half*)h1, nullptr);
  // layer 2 (output, U=64, last state only, f32 out)
  gemm_mfma<64, MODE_F16><<<dim3(2048,4), 256, 0, stream>>>(h1, Wko, bo, masks + 262144, zin);
  rec4_kernel<64, false><<<256, 256, 0, stream>>>(zin, Wro, nullptr, out);
}

// Round 10
// 1860.556 us; speedup vs baseline: 1.2237x; 1.2237x over previous
//
#include <hip/hip_runtime.h>
#include <hip/hip_bf16.h>
#include <hip/hip_fp16.h>
#include <stdint.h>

// ============================================================================
// LSTMEncoder (3-layer Keras LSTM, per-gate input dropout 0.6, threefry RNG)
//   L0: x[256,1024,128] -> h0 ; L1: h0 -> h1 ; L2: h1 -> h_last[256,64] (f32)
// Round 10: rec micro-bundle + A/B. Three rec structures all ~1700 cyc/step
// with VALUBusy 58% >> hand-counted insts => hidden VALU work. Fixes:
//   - gates via v_rcp/v_exp2 builtins (no -ffast-math: plain 1/x was an
//     8-inst IEEE div expansion x5 per step, on the serial chain)
//   - no explicit pre-MFMA lgkm drain (compiler emits counted waits)
//   - A/B: VAR0 (layer0) sched_barrier-fenced publish vs VAR1 (layer1,2)
//     single fused "lgkmcnt(0); s_barrier" asm with memory clobber.
//   gemm_mfma / mask_kernel unchanged (verified round 6).
// Workspace: masks(1.5MB) + z_in f16(256MB) + h0,h1 f16(64MB ea)
// ============================================================================

#define MODE_F32  0
#define MODE_F16  2

typedef _Float16 f16x8 __attribute__((ext_vector_type(8)));
typedef float    f32x4 __attribute__((ext_vector_type(4)));

__device__ __forceinline__ float h16f(uint16_t b){
  __half_raw hr; hr.x = b; return __half2float(__half(hr));
}

__device__ __forceinline__ float fexp2(float x){
#if __has_builtin(__builtin_amdgcn_exp2f)
  return __builtin_amdgcn_exp2f(x);
#else
  return exp2f(x);
#endif
}
__device__ __forceinline__ float frcp(float x){
#if __has_builtin(__builtin_amdgcn_rcpf)
  return __builtin_amdgcn_rcpf(x);
#else
  return 1.0f/x;
#endif
}
#define LOG2E  1.4426950408889634f
#define LOG2E2 2.8853900817779268f

// ---------------- dtype helpers ----------------
template<int M>
__device__ __forceinline__ void cvt8(const void* p, size_t i, float* o){
  if constexpr (M == MODE_F32){
    const float* f = (const float*)p + i;
    float4 a = *(const float4*)f;
    float4 b = *(const float4*)(f + 4);
    o[0]=a.x; o[1]=a.y; o[2]=a.z; o[3]=a.w;
    o[4]=b.x; o[5]=b.y; o[6]=b.z; o[7]=b.w;
  } else {
    uint4 r = *(const uint4*)((const uint16_t*)p + i);
    uint32_t hw[4] = {r.x, r.y, r.z, r.w};
    #pragma unroll
    for (int q=0;q<4;q++){
      o[2*q]   = h16f((uint16_t)(hw[q] & 0xffffu));
      o[2*q+1] = h16f((uint16_t)(hw[q] >> 16));
    }
  }
}

// ---------------- K2: JAX threefry2x32 (partitionable) masks ----------------
__device__ __forceinline__ void tf2x32(uint32_t k0, uint32_t k1,
                                       uint32_t& x0, uint32_t& x1){
  uint32_t ks2 = k0 ^ k1 ^ 0x1BD11BDAu;
  x0 += k0; x1 += k1;
#define TF_R(r) { x0 += x1; x1 = (x1<<r)|(x1>>(32-r)); x1 ^= x0; }
  TF_R(13) TF_R(15) TF_R(26) TF_R(6)  x0 += k1;  x1 += ks2 + 1u;
  TF_R(17) TF_R(29) TF_R(16) TF_R(24) x0 += ks2; x1 += k0  + 2u;
  TF_R(13) TF_R(15) TF_R(26) TF_R(6)  x0 += k0;  x1 += k1  + 3u;
  TF_R(17) TF_R(29) TF_R(16) TF_R(24) x0 += k1;  x1 += ks2 + 4u;
  TF_R(13) TF_R(15) TF_R(26) TF_R(6)  x0 += ks2; x1 += k0  + 5u;
#undef TF_R
}

__device__ __forceinline__ float bern_mask(uint32_t bits){
  float u = __uint_as_float((bits >> 9) | 0x3f800000u) - 1.0f;
  return (u < 0.4f) ? 2.5f : 0.0f;
}

__global__ void mask_kernel(float* __restrict__ masks){
  int gid = blockIdx.x * 256 + threadIdx.x;     // [0, 3*131072)
  int layer = gid >> 17;
  uint32_t i = (uint32_t)(gid & 131071);
  uint32_t k0 = 0u, k1 = (uint32_t)layer;
  tf2x32(0u, 4347u, k0, k1);                    // foldlike split
  uint32_t x0 = 0u, x1 = i;
  tf2x32(k0, k1, x0, x1);                       // partitionable bits
  masks[gid] = bern_mask(x0 ^ x1);
}

// ---------------- K3: input-projection GEMM via MFMA f16 ----------------
// (unchanged — verified round 6)
template<int U, int AM>
__global__ __launch_bounds__(256) void gemm_mfma(
    const void*  __restrict__ A,
    const float* __restrict__ W,
    const float* __restrict__ bias,
    const float* __restrict__ maskL,   // [4][256][128]
    __half* __restrict__ Z)
{
  constexpr int WC   = 4*U;
  constexpr int HALF = U/2;
  __shared__ _Float16 As [128][128];
  __shared__ _Float16 Bst[U  ][128];   // transposed: [col][k]
  const int tid  = threadIdx.x;
  const int r0   = blockIdx.x * 128;
  const int gate = blockIdx.y;
  const int bb   = blockIdx.x >> 3;    // batch (8 row-tiles per batch)
  const float* mrow = maskL + gate*32768 + bb*128;

  // ---- stage A: (x or h) * mask -> f16, swizzled ----
  {
    const int r  = tid >> 1;
    const int kh = (tid & 1) * 64;
    #pragma unroll
    for (int c=0;c<8;c++){
      int k0 = kh + c*8;
      float av[8]; cvt8<AM>(A, (size_t)(r0+r)*128 + k0, av);
      float4 m0 = *(const float4*)(mrow+k0);
      float4 m1 = *(const float4*)(mrow+k0+4);
      _Float16* dst = &As[r][k0 ^ ((r&7)<<3)];
      dst[0]=(_Float16)(av[0]*m0.x); dst[1]=(_Float16)(av[1]*m0.y);
      dst[2]=(_Float16)(av[2]*m0.z); dst[3]=(_Float16)(av[3]*m0.w);
      dst[4]=(_Float16)(av[4]*m1.x); dst[5]=(_Float16)(av[5]*m1.y);
      dst[6]=(_Float16)(av[6]*m1.z); dst[7]=(_Float16)(av[7]*m1.w);
    }
  }
  // ---- stage B: Wk gate slice, transposed + swizzled ----
  {
    const int d  = tid >> 1;
    const int ch = (tid & 1) * HALF;
    #pragma unroll
    for (int cc=0; cc<HALF/8; ++cc){
      int c0 = ch + cc*8;
      const float* wp = W + (size_t)d*WC + gate*U + c0;
      float4 w0 = *(const float4*)wp;
      float4 w1 = *(const float4*)(wp+4);
      float wv[8] = {w0.x,w0.y,w0.z,w0.w,w1.x,w1.y,w1.z,w1.w};
      #pragma unroll
      for (int q=0;q<8;q++){
        int c = c0 + q;
        Bst[c][d ^ ((c&7)<<3)] = (_Float16)wv[q];
      }
    }
  }
  __syncthreads();

  // ---- MFMA compute ----
  const int l  = tid & 63;
  const int w  = tid >> 6;
  const int lr = l & 15;
  const int kg = (l >> 4) * 8;
  constexpr int MF = (U==128) ? 4 : 2;         // m-frags per wave
  const int wr = (U==128) ? ((w>>1)*64) : (w*32);
  const int wc = (U==128) ? ((w&1)*64) : 0;

  f32x4 zz = {0.f,0.f,0.f,0.f};
  f32x4 acc[MF][4];
  #pragma unroll
  for (int m=0;m<MF;m++)
    #pragma unroll
    for (int n=0;n<4;n++) acc[m][n] = zz;

  #pragma unroll
  for (int ks=0; ks<4; ++ks){
    const int kb = ks*32 + kg;
    f16x8 af[MF], bf[4];
    #pragma unroll
    for (int m=0;m<MF;m++){
      int r = wr + m*16 + lr;
      af[m] = *(const f16x8*)&As[r][kb ^ ((r&7)<<3)];
    }
    #pragma unroll
    for (int n=0;n<4;n++){
      int c = wc + n*16 + lr;
      bf[n] = *(const f16x8*)&Bst[c][kb ^ ((c&7)<<3)];
    }
    #pragma unroll
    for (int m=0;m<MF;m++)
      #pragma unroll
      for (int n=0;n<4;n++)
        acc[m][n] = __builtin_amdgcn_mfma_f32_16x16x32_f16(af[m], bf[n], acc[m][n], 0, 0, 0);
  }

  // ---- epilogue: + bias, f16 planar stores ----
  const int crow = (l>>4)*4;
  float bv[4];
  #pragma unroll
  for (int n=0;n<4;n++) bv[n] = bias[gate*U + wc + n*16 + lr];
  #pragma unroll
  for (int m=0;m<MF;m++){
    #pragma unroll
    for (int n=0;n<4;n++){
      int cc = wc + n*16 + lr;
      #pragma unroll
      for (int j=0;j<4;j++){
        int rr = wr + m*16 + crow + j;
        Z[(size_t)(r0+rr)*WC + gate*U + cc] = __float2half(acc[m][n][j] + bv[n]);
      }
    }
  }
}

// ---------------- K4: recurrence v5 (MFMA + LDS z tiles, fast gates) -------
// 1 block per batch row, 4U threads. Wave w owns u-block w*16..+15; Wr slice
// as B-frags in regs. z: 32-step LDS tiles (global_load_lds w16, dbuf).
// h: f16 double-buffered LDS, one barrier/step. Gates: rcp/exp2 builtins.
// VAR0: sched_barrier-fenced publish. VAR1: fused lgkm+barrier asm, no fences.
template<int U, bool SEQ, int VAR>
__global__ __launch_bounds__(4*U, 1) void rec5_kernel(
    const __half* __restrict__ Zin,     // [256][1024][4U] planar [g*U+u]
    const float*  __restrict__ Wr,      // [U][4U]
    __half* __restrict__ Hseq,          // [256][1024][U]  (SEQ)
    float*  __restrict__ Hlast)         // [256][U]        (!SEQ)
{
  constexpr int C   = 4*U;
  constexpr int KS  = U/32;             // mfma k-steps over h-dim
  constexpr int TS  = 32;               // steps per z tile
  constexpr int TBH = TS*C;             // halfwords per tile
  constexpr int NCH = 4;                // (TS*C*2) / (4U*16)
  const int row = blockIdx.x;
  const int tid = threadIdx.x;
  const int l   = tid & 63;
  const int w   = tid >> 6;
  const int lr  = l & 15;
  const int kg  = (l >> 4) * 8;
  const int u   = w*16 + lr;

  __shared__ _Float16 zt[2][TBH];       // z tiles (64KB @U=128)
  __shared__ _Float16 hbuf[2][U];

  // B fragments: bf[g][ks][j] = Wr[ks*32+kg+j][g*U + u]  (one-time load)
  f16x8 bf[4][KS];
  #pragma unroll
  for (int g=0; g<4; ++g)
    #pragma unroll
    for (int ks=0; ks<KS; ++ks)
      #pragma unroll
      for (int j=0; j<8; ++j)
        bf[g][ks][j] = (_Float16)Wr[(size_t)(ks*32 + kg + j)*C + g*U + u];

  if (tid < U) hbuf[0][tid] = (_Float16)0.0f;
  float cst = 0.0f;

  const char* zrow = (const char*)Zin + (size_t)row*1024*C*2;
  auto stage = [&](int tile, int buf){
    const char* gsrc = zrow + (size_t)tile*TBH*2;
    char* lbase = (char*)&zt[buf][0];
    #pragma unroll
    for (int c=0; c<NCH; ++c){
      int off = c*(4*U*16) + tid*16;
      __builtin_amdgcn_global_load_lds(
          (const uint32_t*)(gsrc + off),
          (uint32_t*)(lbase + c*(4*U*16) + w*1024),
          16, 0, 0);
    }
  };
  stage(0, 0);

  uint16_t* hsq = nullptr;
  if constexpr (SEQ) hsq = (uint16_t*)Hseq + (size_t)row*1024*U + u;

  // wait: tile0 staged (vm) + hbuf init (lgkm), all waves
  asm volatile("s_waitcnt vmcnt(0) lgkmcnt(0)" ::: "memory");
  __builtin_amdgcn_s_barrier();

  for (int tile=0; tile<1024/TS; ++tile){
    const int buf = tile & 1;
    if (tile+1 < 1024/TS) stage(tile+1, buf^1);

    #pragma unroll 1
    for (int s8=0; s8<TS/8; ++s8){
      uint16_t hr[8];
      #pragma unroll
      for (int r8=0; r8<8; ++r8){               // static r8 -> static hr index
        const int s  = s8*8 + r8;
        const int tt = tile*TS + s;
        const int hb = r8 & 1;                  // == tt&1
        // ---- LDS reads (compiler inserts counted lgkm waits) ----
        f16x8 af[KS];
        #pragma unroll
        for (int ks=0; ks<KS; ++ks)
          af[ks] = *(const f16x8*)&hbuf[hb][ks*32 + kg];
        float zg0 = (float)zt[buf][s*C         + u];
        float zg1 = (float)zt[buf][s*C +   U   + u];
        float zg2 = (float)zt[buf][s*C + 2*U   + u];
        float zg3 = (float)zt[buf][s*C + 3*U   + u];
        // ---- z + h.Wr on matrix pipe (D rows identical) ----
        f32x4 acc[4];
        acc[0] = (f32x4){zg0,zg0,zg0,zg0};
        acc[1] = (f32x4){zg1,zg1,zg1,zg1};
        acc[2] = (f32x4){zg2,zg2,zg2,zg2};
        acc[3] = (f32x4){zg3,zg3,zg3,zg3};
        #pragma unroll
        for (int g=0; g<4; ++g)
          #pragma unroll
          for (int ks=0; ks<KS; ++ks)
            acc[g] = __builtin_amdgcn_mfma_f32_16x16x32_f16(af[ks], bf[g][ks], acc[g], 0, 0, 0);
        // ---- gates (rcp/exp2, no IEEE div) ----
        float gi = frcp(1.0f + fexp2(-LOG2E * acc[0][0]));
        float gf = frcp(1.0f + fexp2(-LOG2E * acc[1][0]));
        float gg = 1.0f - 2.0f*frcp(fexp2(LOG2E2 * acc[2][0]) + 1.0f);
        float go = frcp(1.0f + fexp2(-LOG2E * acc[3][0]));
        cst = fmaf(gf, cst, gi*gg);
        float h = go * (1.0f - 2.0f*frcp(fexp2(LOG2E2 * cst) + 1.0f));
        __half hh = __float2half(h);
        hr[r8] = *(uint16_t*)&hh;
        if (l < 16){
          hbuf[hb ^ 1][u] = *(_Float16*)&hh;
          if constexpr (!SEQ){
            if (tt == 1023) Hlast[(size_t)row*U + u] = h;
          }
        }
        // ---- publish h (vm stays in flight) ----
        if constexpr (VAR == 0){
          __builtin_amdgcn_sched_barrier(0);
          asm volatile("s_waitcnt lgkmcnt(0)");
          __builtin_amdgcn_s_barrier();
          __builtin_amdgcn_sched_barrier(0);
        } else {
          asm volatile("s_waitcnt lgkmcnt(0)\n\ts_barrier" ::: "memory");
        }
      }
      // ---- burst Hseq stores (8 steps; acks drained at tile edge) ----
      if constexpr (SEQ){
        if (l < 16){
          uint16_t* hp = hsq + (size_t)(tile*TS + s8*8)*U;
          #pragma unroll
          for (int j=0; j<8; ++j) hp[(size_t)j*U] = hr[j];
        }
      }
    }
    // ---- tile edge: staging + store acks drained, all waves ----
    if (tile+1 < 1024/TS){
      asm volatile("s_waitcnt vmcnt(0)" ::: "memory");
      __builtin_amdgcn_s_barrier();
    }
  }
}

// ---------------- host launch ----------------
extern "C" void kernel_launch(void* const* d_in, const int* in_sizes, int n_in,
                              void* d_out, int out_size, void* d_ws, size_t ws_size,
                              hipStream_t stream)
{
  (void)in_sizes; (void)n_in; (void)out_size; (void)ws_size;
  const void*  x   = d_in[0];
  const float* Wk0 = (const float*)d_in[1];
  const float* Wr0 = (const float*)d_in[2];
  const float* b0  = (const float*)d_in[3];
  const float* Wk1 = (const float*)d_in[4];
  const float* Wr1 = (const float*)d_in[5];
  const float* b1  = (const float*)d_in[6];
  const float* Wko = (const float*)d_in[7];
  const float* Wro = (const float*)d_in[8];
  const float* bo  = (const float*)d_in[9];

  char* ws = (char*)d_ws;
  float*  masks = (float*)(ws + 256);                           // 1.5 MB
  __half* zin   = (__half*)(ws + 256 + 3*131072*4);             // 256 MB
  __half* h0    = (__half*)((char*)zin + (size_t)262144*512*2); // 64 MB
  __half* h1    = h0 + (size_t)262144*128;                      // 64 MB
  float*  out   = (float*)d_out;

  mask_kernel<<<1536, 256, 0, stream>>>(masks);

  // layer 0 (A = x, f32) — rec VAR0 (fenced publish)
  gemm_mfma<128, MODE_F32><<<dim3(2048,4), 256, 0, stream>>>(x, Wk0, b0, masks, zin);
  rec5_kernel<128, true, 0><<<256, 512, 0, stream>>>(zin, Wr0, (__half*)h0, nullptr);
  // layer 1 (A = h0, f16 ours) — rec VAR1 (fused asm publish, unfenced)
  gemm_mfma<128, MODE_F16><<<dim3(2048,4), 256, 0, stream>>>(h0, Wk1, b1, masks + 131072, zin);
  rec5_kernel<128, true, 1><<<256, 512, 0, stream>>>(zin, Wr1, (__half*)h1, nullptr);
  // layer 2 (output, U=64, last state only, f32 out) — VAR1
  gemm_mfma<64, MODE_F16><<<dim3(2048,4), 256, 0, stream>>>(h1, Wko, bo, masks + 262144, zin);
  rec5_kernel<64, false, 1><<<256, 256, 0, stream>>>(zin, Wro, nullptr, out);
}